// Round 14
// baseline (270.427 us; speedup 1.0000x reference)
//
#include <hip/hip_runtime.h>
#include <hip/hip_fp16.h>

#define N_NODES   50000
#define N_EDGES   800000
#define D         64
#define N_CLASSES 10
#define N_GRAPHS  128
#define ELLW      48   // max in-degree bound: Poisson(16), P(any deg>=48) ~ 1e-6; input fixed
#define CPAD      16   // counters padded to one per 64B line (atomic line-serialization fix)
#define NXCD      8
#define DPART     (N_NODES / NXCD)   // 6250 dst nodes per XCD partition

// ELL entry is PACKED 4B: low16 = src node id (<50000<65536), high16 = ew as fp16.
// Activations are PRE-SCALED: xwh'[i] = dinv[i]*(h@W)[i] -> gather is dinv-free:
//   agg[i] = dv*( xwh'[i] + sum_j ew_j * xwh'[src_j] ) + b
// Round-14 gather: SGPR meta (round-13) + half2 lanes (round-7 mechanism, now
// viable): lane covers 2 cols via one 4B load; wave-halves split the row pair.
// 8 VMEM instructions per 8-edge batch instead of 16, same bytes in flight.
// (Round-7's regression was per-lane meta VGPR=92; SGPR meta removes that.)

__device__ __forceinline__ float unpack_ew(int p) {
    return __half2float(__ushort_as_half((unsigned short)((unsigned)p >> 16)));
}
__device__ __forceinline__ float h_lo(unsigned v) {
    return __half2float(__ushort_as_half((unsigned short)(v & 0xFFFF)));
}
__device__ __forceinline__ float h_hi(unsigned v) {
    return __half2float(__ushort_as_half((unsigned short)(v >> 16)));
}

// ---------------- setup kernels ----------------

// XCD-partitioned scatter (round-2 proven form: ~47us, occ 62%). Round-4's
// nontemporal scan REGRESSED; ~31MB residual write traffic is structural
// (~1-2 entries per ELL line per fill window). Latency/atomic floor; leave it.
__global__ __launch_bounds__(256) void ell_scatter(const int* __restrict__ src,
                                                   const int* __restrict__ dst,
                                                   const float* __restrict__ ew,
                                                   int* __restrict__ count,
                                                   unsigned int* __restrict__ ell) {
    const int grp = blockIdx.x & (NXCD - 1);
    const int ord = blockIdx.x >> 3;          // 0..390
    const int lo  = grp * DPART;
#pragma unroll
    for (int i = 0; i < 8; ++i) {
        int e = ord * 2048 + i * 256 + threadIdx.x;
        if (e < N_EDGES) {
            int d = dst[e];
            if ((unsigned)(d - lo) < (unsigned)DPART) {
                int s = src[e];
                float w = ew[e];
                int c = atomicAdd(&count[d * CPAD], 1);
                if (c < ELLW) {
                    ell[d * ELLW + c] = (unsigned int)s |
                        ((unsigned int)__half_as_ushort(__float2half_rn(w)) << 16);
                }
            }
        }
    }
}

// Wave per node: deg = 1 + sum(ew over slots), dinv = rsqrt(deg). Atomic-free.
__global__ __launch_bounds__(256) void node_dinv(const int* __restrict__ count,
                                                 const unsigned int* __restrict__ ell,
                                                 float* __restrict__ dinv) {
    const int lane = threadIdx.x & 63;
    const int gwave = (blockIdx.x * blockDim.x + threadIdx.x) >> 6;
    const int nw = (gridDim.x * blockDim.x) >> 6;
    for (int i = gwave; i < N_NODES; i += nw) {
        int cnt = min(count[i * CPAD], ELLW);
        float w = (lane < cnt) ? unpack_ew((int)ell[i * ELLW + lane]) : 0.0f;
#pragma unroll
        for (int off = 32; off >= 1; off >>= 1) w += __shfl_xor(w, off);
        if (lane == 0) dinv[i] = rsqrtf(1.0f + w);
    }
}

// ---------------- shared half2 dual-row gather core (round-14) ----------------

// PRECONDITION: q is a wave-uniform SGPR value (caller readfirstlanes it).
// Lane covers cols {2*sub, 2*sub+1} of row (2q + hf), hf = lane>>5.
// Meta for BOTH rows via uniform s_load -> SGPR; per-edge the half's packed
// word is selected with one v_cndmask. Out-of-range slots clamp p->0
// (s_cselect): ew unpacks to 0.0, address hits hot row 0 (proven r7/8).
// Returns alo/ahi = cols {2sub,2sub+1} of acc for this half's row.
__device__ __forceinline__ void gather_h2(const int* __restrict__ count,
                                          const unsigned int* __restrict__ ell,
                                          const __half* __restrict__ xwh,
                                          int q, int sub, int hf,
                                          float& alo, float& ahi) {
    const int rowA = 2 * q, rowB = 2 * q + 1;
    int cntA = min(count[rowA * CPAD], ELLW);
    int cntB = min(count[rowB * CPAD], ELLW);
    const int4* mA = (const int4*)(ell + (size_t)rowA * ELLW);
    const int4* mB = (const int4*)(ell + (size_t)rowB * ELLW);
    const int rowh = rowA + hf;
    unsigned sv = *(const unsigned*)(xwh + (size_t)rowh * D + 2 * sub);  // self
    alo = h_lo(sv);
    ahi = h_hi(sv);
    int cm = max(cntA, cntB);
    for (int j = 0; j < cm; j += 8) {
        int4 a0 = mA[j / 4 + 0];   // uniform addr -> s_load_dwordx4
        int4 a1 = mA[j / 4 + 1];
        int4 b0 = mB[j / 4 + 0];
        int4 b1 = mB[j / 4 + 1];
        int pA[8] = {a0.x, a0.y, a0.z, a0.w, a1.x, a1.y, a1.z, a1.w};
        int pB[8] = {b0.x, b0.y, b0.z, b0.w, b1.x, b1.y, b1.z, b1.w};
#pragma unroll
        for (int t = 0; t < 8; ++t) pA[t] = (j + t < cntA) ? pA[t] : 0;  // s_cselect
#pragma unroll
        for (int t = 0; t < 8; ++t) pB[t] = (j + t < cntB) ? pB[t] : 0;
        int ps[8];
#pragma unroll
        for (int t = 0; t < 8; ++t) ps[t] = hf ? pB[t] : pA[t];  // v_cndmask
        unsigned vv[8];
#pragma unroll
        for (int t = 0; t < 8; ++t)
            vv[t] = *(const unsigned*)(xwh + (size_t)(ps[t] & 0xFFFF) * D + 2 * sub);
#pragma unroll
        for (int t = 0; t < 8; ++t) {
            float w = unpack_ew(ps[t]);
            alo = fmaf(h_lo(vv[t]), w, alo);
            ahi = fmaf(h_hi(vv[t]), w, ahi);
        }
    }
}

// ---------------- per-layer kernels ----------------

// xwh' = dinv[row] * (in @ W), QUAD-ROW vector path (round-12 proven: one
// coalesced per-lane float4 load = 4-row quad staged per-wave in LDS, re-read
// as uniform broadcasts vs W[:,lane] in VGPRs).
__global__ __launch_bounds__(256) void gemm_rows(const float* __restrict__ in,
                                                 const float* __restrict__ W,
                                                 const float* __restrict__ dinv,
                                                 __half* __restrict__ xwh) {
    __shared__ float  Wl[D * D];      // 16KB
    __shared__ float4 xq[4][64];      // 4KB: per-wave quad stage
    for (int i = threadIdx.x; i < D * D; i += blockDim.x) Wl[i] = W[i];
    __syncthreads();

    const int lane = threadIdx.x & 63;
    const int wid  = threadIdx.x >> 6;
    float w[D];
#pragma unroll
    for (int k = 0; k < D; ++k) w[k] = Wl[k * D + lane];  // 2-way bank alias: free

    const int q = (blockIdx.x * blockDim.x + threadIdx.x) >> 6;  // quad id, exact
    const int r0 = q * 4;

    xq[wid][lane] = ((const float4*)(in + (size_t)r0 * D))[lane];  // 1KB coalesced
    float dv0 = dinv[r0 + 0], dv1 = dinv[r0 + 1];
    float dv2 = dinv[r0 + 2], dv3 = dinv[r0 + 3];
    const float4* xr = (const float4*)xq[wid];
    float acc0 = 0.0f, acc1 = 0.0f, acc2 = 0.0f, acc3 = 0.0f;
#pragma unroll
    for (int k4 = 0; k4 < D / 4; ++k4) {
        float4 x0 = xr[0 * 16 + k4];  // uniform addr -> LDS broadcast
        float4 x1 = xr[1 * 16 + k4];
        float4 x2 = xr[2 * 16 + k4];
        float4 x3 = xr[3 * 16 + k4];
        float w0 = w[4 * k4 + 0], w1 = w[4 * k4 + 1];
        float w2 = w[4 * k4 + 2], w3 = w[4 * k4 + 3];
        acc0 = fmaf(x0.x, w0, acc0); acc0 = fmaf(x0.y, w1, acc0);
        acc0 = fmaf(x0.z, w2, acc0); acc0 = fmaf(x0.w, w3, acc0);
        acc1 = fmaf(x1.x, w0, acc1); acc1 = fmaf(x1.y, w1, acc1);
        acc1 = fmaf(x1.z, w2, acc1); acc1 = fmaf(x1.w, w3, acc1);
        acc2 = fmaf(x2.x, w0, acc2); acc2 = fmaf(x2.y, w1, acc2);
        acc2 = fmaf(x2.z, w2, acc2); acc2 = fmaf(x2.w, w3, acc2);
        acc3 = fmaf(x3.x, w0, acc3); acc3 = fmaf(x3.y, w1, acc3);
        acc3 = fmaf(x3.z, w2, acc3); acc3 = fmaf(x3.w, w3, acc3);
    }
    xwh[(size_t)(r0 + 0) * D + lane] = __float2half(acc0 * dv0);
    xwh[(size_t)(r0 + 1) * D + lane] = __float2half(acc1 * dv1);
    xwh[(size_t)(r0 + 2) * D + lane] = __float2half(acc2 * dv2);
    xwh[(size_t)(r0 + 3) * D + lane] = __float2half(acc3 * dv3);
}

// FUSED agg+gemm (layers 1->2 and 2->3), half2 dual-row, one pair per wave.
//   s    = relu( dv*gather + bias )    (lane holds 2 cols of its half's row)
//   xout = dv * (s @ W)                (next layer's pre-scaled xwh')
// Epilogue: per-half LDS row stage (wave-synchronous), uniform float4
// broadcasts vs W float2 columns (round-7's epilogue, measured fine).
__global__ __launch_bounds__(256) void aggemm(const int* __restrict__ count,
                                              const unsigned int* __restrict__ ell,
                                              const float* __restrict__ dinv,
                                              const __half* __restrict__ xin,
                                              const float* __restrict__ bias,
                                              const float* __restrict__ W,
                                              __half* __restrict__ xout) {
    __shared__ float Wl[D * D];        // 16KB
    __shared__ float rb[4][2][D];      // 2KB: per-wave, per-half fp32 row
    for (int i = threadIdx.x; i < D * D; i += blockDim.x) Wl[i] = W[i];
    __syncthreads();

    const int lane = threadIdx.x & 63;
    const int sub  = lane & 31;
    const int hf   = lane >> 5;
    const int wid  = threadIdx.x >> 6;
    const int q = __builtin_amdgcn_readfirstlane(
        (blockIdx.x * blockDim.x + threadIdx.x) >> 6);   // pair id, SGPR
    const float2 bv = *(const float2*)&bias[2 * sub];

    const int rowh = 2 * q + hf;
    float alo, ahi;
    gather_h2(count, ell, xin, q, sub, hf, alo, ahi);
    float dv = dinv[rowh];
    float s0 = fmaxf(fmaf(alo, dv, bv.x), 0.0f);   // fused layers always relu
    float s1 = fmaxf(fmaf(ahi, dv, bv.y), 0.0f);
    *(float2*)&rb[wid][hf][2 * sub] = make_float2(s0, s1);
    const float4* r4 = (const float4*)rb[wid][hf];
    float o0 = 0.0f, o1 = 0.0f;
#pragma unroll
    for (int k4 = 0; k4 < D / 4; ++k4) {
        float4 r = r4[k4];  // uniform addr within half -> LDS broadcast
#pragma unroll
        for (int i = 0; i < 4; ++i) {
            float rk = (i == 0) ? r.x : (i == 1) ? r.y : (i == 2) ? r.z : r.w;
            float2 wv = *(const float2*)&Wl[(4 * k4 + i) * D + 2 * sub];
            o0 = fmaf(rk, wv.x, o0);
            o1 = fmaf(rk, wv.y, o1);
        }
    }
    *(__half2*)(xout + (size_t)rowh * D + 2 * sub) = __floats2half2_rn(o0 * dv, o1 * dv);
}

// Plain aggregation (layer-3 output), half2 dual-row, one pair per wave.
__global__ __launch_bounds__(256) void node_agg(const int* __restrict__ count,
                                                const unsigned int* __restrict__ ell,
                                                const float* __restrict__ dinv,
                                                const __half* __restrict__ xwh,
                                                const float* __restrict__ bias,
                                                float* __restrict__ agg) {
    const int lane = threadIdx.x & 63;
    const int sub  = lane & 31;
    const int hf   = lane >> 5;
    const int q = __builtin_amdgcn_readfirstlane(
        (blockIdx.x * blockDim.x + threadIdx.x) >> 6);   // pair id, SGPR
    const float2 bv = *(const float2*)&bias[2 * sub];

    const int rowh = 2 * q + hf;
    float alo, ahi;
    gather_h2(count, ell, xwh, q, sub, hf, alo, ahi);
    float dv = dinv[rowh];
    *(float2*)(agg + (size_t)rowh * D + 2 * sub) =
        make_float2(fmaf(alo, dv, bv.x), fmaf(ahi, dv, bv.y));
}

// ---------------- pooling + classifier ----------------

// batch sorted: contiguous chunk per wave, register accumulate, flush per boundary.
__global__ __launch_bounds__(256) void pool(const float* __restrict__ agg3,
                                            const int* __restrict__ batch,
                                            float* __restrict__ pooled,
                                            float* __restrict__ cnt) {
    const int lane = threadIdx.x & 63;
    const int gwave = (blockIdx.x * blockDim.x + threadIdx.x) >> 6;
    const int nw = (gridDim.x * blockDim.x) >> 6;
    const int chunk = (N_NODES + nw - 1) / nw;
    int r0 = gwave * chunk;
    int r1 = min(r0 + chunk, N_NODES);
    if (r0 >= r1) return;

    int g = batch[r0];
    float acc = 0.0f;
    int c = 0;
    for (int row = r0; row < r1; ++row) {
        int gg = batch[row];
        if (gg != g) {
            atomicAdd(&pooled[g * D + lane], acc);
            if (lane == 0) atomicAdd(&cnt[g], (float)c);
            g = gg; acc = 0.0f; c = 0;
        }
        acc += agg3[(size_t)row * D + lane];
        ++c;
    }
    atomicAdd(&pooled[g * D + lane], acc);
    if (lane == 0) atomicAdd(&cnt[g], (float)c);
}

__global__ __launch_bounds__(64) void final_lin(const float* __restrict__ pooled,
                                                const float* __restrict__ cnt,
                                                const float* __restrict__ Wlin,
                                                const float* __restrict__ blin,
                                                float* __restrict__ out) {
    __shared__ float row[D];
    int g = blockIdx.x;
    int t = threadIdx.x;
    float c = fmaxf(cnt[g], 1.0f);
    row[t] = pooled[g * D + t] / c;
    __syncthreads();
    if (t < N_CLASSES) {
        float acc = blin[t];
#pragma unroll
        for (int k = 0; k < D; ++k) acc = fmaf(row[k], Wlin[k * N_CLASSES + t], acc);
        out[g * N_CLASSES + t] = acc;
    }
}

// ---------------- launch ----------------

extern "C" void kernel_launch(void* const* d_in, const int* in_sizes, int n_in,
                              void* d_out, int out_size, void* d_ws, size_t ws_size,
                              hipStream_t stream) {
    const float* x     = (const float*)d_in[0];
    const int*   ei    = (const int*)d_in[1];
    const int*   src   = ei;
    const int*   dst   = ei + N_EDGES;
    const int*   batch = (const int*)d_in[2];
    const float* ew    = (const float*)d_in[3];
    const float* W1    = (const float*)d_in[4];
    const float* b1    = (const float*)d_in[5];
    const float* W2    = (const float*)d_in[6];
    const float* b2    = (const float*)d_in[7];
    const float* W3    = (const float*)d_in[8];
    const float* b3    = (const float*)d_in[9];
    const float* Wlin  = (const float*)d_in[10];
    const float* blin  = (const float*)d_in[11];
    float* out = (float*)d_out;

    // workspace layout (4B units)
    float*        ws     = (float*)d_ws;
    __half*       xwhA   = (__half*)ws;                    // 50000*64 half = 1,600,000 floats
    __half*       xwhB   = (__half*)(ws + 1600000);        // double buffer (fused layers)
    float*        agg3   = ws + 3200000;                   // 3,200,000 (fp32 layer-3 out)
    unsigned int* ell    = (unsigned int*)(ws + 6400000);  // 50000*48 u32 = 2,400,000 floats
    float*        dinv   = ws + 8800000;                   // 50,000
    int*          count  = (int*)(ws + 8850000);           // 50000*16 = 800,000 (line-padded)
    float*        pooled = ws + 9650000;                   // 8,192
    float*        cnt    = ws + 9658192;                   // 128
    // total ~9.66M * 4B = ~38.6 MB

    const int B = 256;

    (void)hipMemsetAsync(count, 0, N_NODES * CPAD * sizeof(int), stream);
    (void)hipMemsetAsync(pooled, 0, (N_GRAPHS * D + N_GRAPHS) * sizeof(float), stream);

    const int pairBlocks = 6250;  // 25000 waves = 25000 pairs, 1 pair/wave exact
    const int quadBlocks = 3125;  // 12500 waves = 12500 quads, 1 quad/wave exact

    // ELL build: 8 groups x 391 blocks; group = bid&7 owns one dst partition.
    ell_scatter<<<391 * NXCD, B, 0, stream>>>(src, dst, ew, count, ell);
    node_dinv<<<3125, B, 0, stream>>>(count, ell, dinv);

    // layer 1 gemm: xwhA = dinv .* (x @ W1)
    gemm_rows<<<quadBlocks, B, 0, stream>>>(x, W1, dinv, xwhA);
    // fused layer 1 agg + layer 2 gemm: xwhB = dinv .* (relu(A^(xwhA)+b1) @ W2)
    aggemm<<<pairBlocks, B, 0, stream>>>(count, ell, dinv, xwhA, b1, W2, xwhB);
    // fused layer 2 agg + layer 3 gemm: xwhA = dinv .* (relu(A^(xwhB)+b2) @ W3)
    aggemm<<<pairBlocks, B, 0, stream>>>(count, ell, dinv, xwhB, b2, W3, xwhA);
    // layer 3 aggregation (no relu): agg3 = A^(xwhA) + b3
    node_agg<<<pairBlocks, B, 0, stream>>>(count, ell, dinv, xwhA, b3, agg3);

    // global mean pool and classifier
    pool<<<196, B, 0, stream>>>(agg3, batch, pooled, cnt);
    final_lin<<<N_GRAPHS, 64, 0, stream>>>(pooled, cnt, Wlin, blin, out);
}

// Round 15
// 257.683 us; speedup vs baseline: 1.0495x; 1.0495x over previous
//
#include <hip/hip_runtime.h>
#include <hip/hip_fp16.h>

#define N_NODES   50000
#define N_EDGES   800000
#define D         64
#define N_CLASSES 10
#define N_GRAPHS  128
#define ELLW      48   // max in-degree bound: Poisson(16), P(any deg>=48) ~ 1e-6; input fixed
#define CPAD      16   // counters padded to one per 64B line (atomic line-serialization fix)
#define NXCD      8
#define DPART     (N_NODES / NXCD)   // 6250 dst nodes per XCD partition

// ELL entry is PACKED 4B: low16 = src node id (<50000<65536), high16 = ew as fp16.
// Activations are PRE-SCALED: xwh'[i] = dinv[i]*(h@W)[i] -> gather is dinv-free:
//   agg[i] = dv*( xwh'[i] + sum_j ew_j * xwh'[src_j] ) + b
// Round-15 gather: QUAD-ROW. Round-13's SGPR meta dropped VGPR to 36, freeing
// headroom below the 64-VGPR occupancy step; round-8 proved concurrent-rows =
// in-flight gathers = speed. 4 rows/wave -> 32 gathers in flight. Full-row
// lanes kept (half2 twice-failed: r7 VGPR, r14 cndmask chain -- dead end).

__device__ __forceinline__ float unpack_ew(int p) {
    return __half2float(__ushort_as_half((unsigned short)((unsigned)p >> 16)));
}

// ---------------- setup kernels ----------------

// XCD-partitioned scatter (round-2 proven form: ~47us, occ 62%). Round-4's
// nontemporal scan REGRESSED; ~31MB residual write traffic is structural
// (~1-2 entries per ELL line per fill window). Latency/atomic floor; leave it.
__global__ __launch_bounds__(256) void ell_scatter(const int* __restrict__ src,
                                                   const int* __restrict__ dst,
                                                   const float* __restrict__ ew,
                                                   int* __restrict__ count,
                                                   unsigned int* __restrict__ ell) {
    const int grp = blockIdx.x & (NXCD - 1);
    const int ord = blockIdx.x >> 3;          // 0..390
    const int lo  = grp * DPART;
#pragma unroll
    for (int i = 0; i < 8; ++i) {
        int e = ord * 2048 + i * 256 + threadIdx.x;
        if (e < N_EDGES) {
            int d = dst[e];
            if ((unsigned)(d - lo) < (unsigned)DPART) {
                int s = src[e];
                float w = ew[e];
                int c = atomicAdd(&count[d * CPAD], 1);
                if (c < ELLW) {
                    ell[d * ELLW + c] = (unsigned int)s |
                        ((unsigned int)__half_as_ushort(__float2half_rn(w)) << 16);
                }
            }
        }
    }
}

// Wave per node: deg = 1 + sum(ew over slots), dinv = rsqrt(deg). Atomic-free.
__global__ __launch_bounds__(256) void node_dinv(const int* __restrict__ count,
                                                 const unsigned int* __restrict__ ell,
                                                 float* __restrict__ dinv) {
    const int lane = threadIdx.x & 63;
    const int gwave = (blockIdx.x * blockDim.x + threadIdx.x) >> 6;
    const int nw = (gridDim.x * blockDim.x) >> 6;
    for (int i = gwave; i < N_NODES; i += nw) {
        int cnt = min(count[i * CPAD], ELLW);
        float w = (lane < cnt) ? unpack_ew((int)ell[i * ELLW + lane]) : 0.0f;
#pragma unroll
        for (int off = 32; off >= 1; off >>= 1) w += __shfl_xor(w, off);
        if (lane == 0) dinv[i] = rsqrtf(1.0f + w);
    }
}

// ---------------- shared quad-row gather core (round-15) ----------------

// PRECONDITION: r0 = 4*q with q a wave-uniform SGPR value. acc[r] =
// xwh'[r0+r] + sum_j ew_j * xwh'[src_j]. One batch loop to max of the 4
// counts (batch granularity 8 absorbs the max-growth: ceil(max4/8) ~=
// ceil(max2/8) for Poisson(16)). Meta via uniform s_load -> SGPR; clamps are
// s_cselect; p->0 slots: ew = 0.0, address hits hot row 0 (proven r7/8).
// 32 row-gathers in flight per batch.
__device__ __forceinline__ void gather_quad(const int* __restrict__ count,
                                            const unsigned int* __restrict__ ell,
                                            const __half* __restrict__ xwh,
                                            int r0, int lane, float acc[4]) {
    int cnt[4];
#pragma unroll
    for (int r = 0; r < 4; ++r) cnt[r] = min(count[(r0 + r) * CPAD], ELLW);
#pragma unroll
    for (int r = 0; r < 4; ++r)
        acc[r] = __half2float(xwh[(size_t)(r0 + r) * D + lane]);  // self (pre-scaled)
    int cm = max(max(cnt[0], cnt[1]), max(cnt[2], cnt[3]));
    for (int j = 0; j < cm; j += 8) {
        int p[4][8];
#pragma unroll
        for (int r = 0; r < 4; ++r) {
            const int4* m = (const int4*)(ell + (size_t)(r0 + r) * ELLW);
            int4 a0 = m[j / 4 + 0];   // uniform addr -> s_load_dwordx4
            int4 a1 = m[j / 4 + 1];
            p[r][0] = a0.x; p[r][1] = a0.y; p[r][2] = a0.z; p[r][3] = a0.w;
            p[r][4] = a1.x; p[r][5] = a1.y; p[r][6] = a1.z; p[r][7] = a1.w;
#pragma unroll
            for (int t = 0; t < 8; ++t)
                p[r][t] = (j + t < cnt[r]) ? p[r][t] : 0;  // s_cselect
        }
        float v[4][8];
#pragma unroll
        for (int r = 0; r < 4; ++r)
#pragma unroll
            for (int t = 0; t < 8; ++t)
                v[r][t] = __half2float(xwh[(size_t)(p[r][t] & 0xFFFF) * D + lane]);
#pragma unroll
        for (int r = 0; r < 4; ++r)
#pragma unroll
            for (int t = 0; t < 8; ++t)
                acc[r] = fmaf(v[r][t], unpack_ew(p[r][t]), acc[r]);
    }
}

// ---------------- per-layer kernels ----------------

// xwh' = dinv[row] * (in @ W), QUAD-ROW vector path (round-12 proven: one
// coalesced per-lane float4 load = 4-row quad staged per-wave in LDS, re-read
// as uniform broadcasts vs W[:,lane] in VGPRs).
__global__ __launch_bounds__(256) void gemm_rows(const float* __restrict__ in,
                                                 const float* __restrict__ W,
                                                 const float* __restrict__ dinv,
                                                 __half* __restrict__ xwh) {
    __shared__ float  Wl[D * D];      // 16KB
    __shared__ float4 xq[4][64];      // 4KB: per-wave quad stage
    for (int i = threadIdx.x; i < D * D; i += blockDim.x) Wl[i] = W[i];
    __syncthreads();

    const int lane = threadIdx.x & 63;
    const int wid  = threadIdx.x >> 6;
    float w[D];
#pragma unroll
    for (int k = 0; k < D; ++k) w[k] = Wl[k * D + lane];  // 2-way bank alias: free

    const int q = (blockIdx.x * blockDim.x + threadIdx.x) >> 6;  // quad id, exact
    const int r0 = q * 4;

    xq[wid][lane] = ((const float4*)(in + (size_t)r0 * D))[lane];  // 1KB coalesced
    float dv0 = dinv[r0 + 0], dv1 = dinv[r0 + 1];
    float dv2 = dinv[r0 + 2], dv3 = dinv[r0 + 3];
    const float4* xr = (const float4*)xq[wid];
    float acc0 = 0.0f, acc1 = 0.0f, acc2 = 0.0f, acc3 = 0.0f;
#pragma unroll
    for (int k4 = 0; k4 < D / 4; ++k4) {
        float4 x0 = xr[0 * 16 + k4];  // uniform addr -> LDS broadcast
        float4 x1 = xr[1 * 16 + k4];
        float4 x2 = xr[2 * 16 + k4];
        float4 x3 = xr[3 * 16 + k4];
        float w0 = w[4 * k4 + 0], w1 = w[4 * k4 + 1];
        float w2 = w[4 * k4 + 2], w3 = w[4 * k4 + 3];
        acc0 = fmaf(x0.x, w0, acc0); acc0 = fmaf(x0.y, w1, acc0);
        acc0 = fmaf(x0.z, w2, acc0); acc0 = fmaf(x0.w, w3, acc0);
        acc1 = fmaf(x1.x, w0, acc1); acc1 = fmaf(x1.y, w1, acc1);
        acc1 = fmaf(x1.z, w2, acc1); acc1 = fmaf(x1.w, w3, acc1);
        acc2 = fmaf(x2.x, w0, acc2); acc2 = fmaf(x2.y, w1, acc2);
        acc2 = fmaf(x2.z, w2, acc2); acc2 = fmaf(x2.w, w3, acc2);
        acc3 = fmaf(x3.x, w0, acc3); acc3 = fmaf(x3.y, w1, acc3);
        acc3 = fmaf(x3.z, w2, acc3); acc3 = fmaf(x3.w, w3, acc3);
    }
    xwh[(size_t)(r0 + 0) * D + lane] = __float2half(acc0 * dv0);
    xwh[(size_t)(r0 + 1) * D + lane] = __float2half(acc1 * dv1);
    xwh[(size_t)(r0 + 2) * D + lane] = __float2half(acc2 * dv2);
    xwh[(size_t)(r0 + 3) * D + lane] = __float2half(acc3 * dv3);
}

// FUSED agg+gemm (layers 1->2 and 2->3), quad-row, one quad per wave.
//   s[r]  = relu( dv[r]*gather + bias )      (fp32, one value/lane/row)
//   xout  = dv[r] * (s[r] @ W)               (next layer's pre-scaled xwh')
// Epilogue: 4 rows staged per-wave in LDS (wave-synchronous); each Wl value
// read ONCE for all 4 rows. W in LDS keeps VGPR low.
__global__ __launch_bounds__(256) void aggemm(const int* __restrict__ count,
                                              const unsigned int* __restrict__ ell,
                                              const float* __restrict__ dinv,
                                              const __half* __restrict__ xin,
                                              const float* __restrict__ bias,
                                              const float* __restrict__ W,
                                              __half* __restrict__ xout) {
    __shared__ float Wl[D * D];        // 16KB
    __shared__ float rb[4][4][D];      // 4KB: per-wave, rows 0..3
    for (int i = threadIdx.x; i < D * D; i += blockDim.x) Wl[i] = W[i];
    __syncthreads();

    const int lane = threadIdx.x & 63;
    const int wid  = threadIdx.x >> 6;
    const int q = __builtin_amdgcn_readfirstlane(
        (blockIdx.x * blockDim.x + threadIdx.x) >> 6);   // quad id, SGPR
    const int r0 = q * 4;
    const float bv = bias[lane];

    float acc[4];
    gather_quad(count, ell, xin, r0, lane, acc);
    float dv[4];
#pragma unroll
    for (int r = 0; r < 4; ++r) dv[r] = dinv[r0 + r];
#pragma unroll
    for (int r = 0; r < 4; ++r)
        rb[wid][r][lane] = fmaxf(fmaf(acc[r], dv[r], bv), 0.0f);  // relu

    const float4* rq[4] = {(const float4*)rb[wid][0], (const float4*)rb[wid][1],
                           (const float4*)rb[wid][2], (const float4*)rb[wid][3]};
    float o0 = 0.0f, o1 = 0.0f, o2 = 0.0f, o3 = 0.0f;
#pragma unroll
    for (int k4 = 0; k4 < D / 4; ++k4) {
        float4 ra = rq[0][k4];  // uniform addr -> LDS broadcast
        float4 rbv = rq[1][k4];
        float4 rc = rq[2][k4];
        float4 rd = rq[3][k4];
        float w0 = Wl[(4 * k4 + 0) * D + lane];
        float w1 = Wl[(4 * k4 + 1) * D + lane];
        float w2 = Wl[(4 * k4 + 2) * D + lane];
        float w3 = Wl[(4 * k4 + 3) * D + lane];
        o0 = fmaf(ra.x, w0, o0);  o0 = fmaf(ra.y, w1, o0);
        o0 = fmaf(ra.z, w2, o0);  o0 = fmaf(ra.w, w3, o0);
        o1 = fmaf(rbv.x, w0, o1); o1 = fmaf(rbv.y, w1, o1);
        o1 = fmaf(rbv.z, w2, o1); o1 = fmaf(rbv.w, w3, o1);
        o2 = fmaf(rc.x, w0, o2);  o2 = fmaf(rc.y, w1, o2);
        o2 = fmaf(rc.z, w2, o2);  o2 = fmaf(rc.w, w3, o2);
        o3 = fmaf(rd.x, w0, o3);  o3 = fmaf(rd.y, w1, o3);
        o3 = fmaf(rd.z, w2, o3);  o3 = fmaf(rd.w, w3, o3);
    }
    xout[(size_t)(r0 + 0) * D + lane] = __float2half(o0 * dv[0]);
    xout[(size_t)(r0 + 1) * D + lane] = __float2half(o1 * dv[1]);
    xout[(size_t)(r0 + 2) * D + lane] = __float2half(o2 * dv[2]);
    xout[(size_t)(r0 + 3) * D + lane] = __float2half(o3 * dv[3]);
}

// Plain aggregation (layer-3 output), quad-row, one quad per wave.
__global__ __launch_bounds__(256) void node_agg(const int* __restrict__ count,
                                                const unsigned int* __restrict__ ell,
                                                const float* __restrict__ dinv,
                                                const __half* __restrict__ xwh,
                                                const float* __restrict__ bias,
                                                float* __restrict__ agg) {
    const int lane = threadIdx.x & 63;
    const int q = __builtin_amdgcn_readfirstlane(
        (blockIdx.x * blockDim.x + threadIdx.x) >> 6);   // quad id, SGPR
    const int r0 = q * 4;
    const float bv = bias[lane];

    float acc[4];
    gather_quad(count, ell, xwh, r0, lane, acc);
#pragma unroll
    for (int r = 0; r < 4; ++r)
        agg[(size_t)(r0 + r) * D + lane] = fmaf(acc[r], dinv[r0 + r], bv);
}

// ---------------- pooling + classifier ----------------

// batch sorted: contiguous chunk per wave, register accumulate, flush per boundary.
__global__ __launch_bounds__(256) void pool(const float* __restrict__ agg3,
                                            const int* __restrict__ batch,
                                            float* __restrict__ pooled,
                                            float* __restrict__ cnt) {
    const int lane = threadIdx.x & 63;
    const int gwave = (blockIdx.x * blockDim.x + threadIdx.x) >> 6;
    const int nw = (gridDim.x * blockDim.x) >> 6;
    const int chunk = (N_NODES + nw - 1) / nw;
    int r0 = gwave * chunk;
    int r1 = min(r0 + chunk, N_NODES);
    if (r0 >= r1) return;

    int g = batch[r0];
    float acc = 0.0f;
    int c = 0;
    for (int row = r0; row < r1; ++row) {
        int gg = batch[row];
        if (gg != g) {
            atomicAdd(&pooled[g * D + lane], acc);
            if (lane == 0) atomicAdd(&cnt[g], (float)c);
            g = gg; acc = 0.0f; c = 0;
        }
        acc += agg3[(size_t)row * D + lane];
        ++c;
    }
    atomicAdd(&pooled[g * D + lane], acc);
    if (lane == 0) atomicAdd(&cnt[g], (float)c);
}

__global__ __launch_bounds__(64) void final_lin(const float* __restrict__ pooled,
                                                const float* __restrict__ cnt,
                                                const float* __restrict__ Wlin,
                                                const float* __restrict__ blin,
                                                float* __restrict__ out) {
    __shared__ float row[D];
    int g = blockIdx.x;
    int t = threadIdx.x;
    float c = fmaxf(cnt[g], 1.0f);
    row[t] = pooled[g * D + t] / c;
    __syncthreads();
    if (t < N_CLASSES) {
        float acc = blin[t];
#pragma unroll
        for (int k = 0; k < D; ++k) acc = fmaf(row[k], Wlin[k * N_CLASSES + t], acc);
        out[g * N_CLASSES + t] = acc;
    }
}

// ---------------- launch ----------------

extern "C" void kernel_launch(void* const* d_in, const int* in_sizes, int n_in,
                              void* d_out, int out_size, void* d_ws, size_t ws_size,
                              hipStream_t stream) {
    const float* x     = (const float*)d_in[0];
    const int*   ei    = (const int*)d_in[1];
    const int*   src   = ei;
    const int*   dst   = ei + N_EDGES;
    const int*   batch = (const int*)d_in[2];
    const float* ew    = (const float*)d_in[3];
    const float* W1    = (const float*)d_in[4];
    const float* b1    = (const float*)d_in[5];
    const float* W2    = (const float*)d_in[6];
    const float* b2    = (const float*)d_in[7];
    const float* W3    = (const float*)d_in[8];
    const float* b3    = (const float*)d_in[9];
    const float* Wlin  = (const float*)d_in[10];
    const float* blin  = (const float*)d_in[11];
    float* out = (float*)d_out;

    // workspace layout (4B units)
    float*        ws     = (float*)d_ws;
    __half*       xwhA   = (__half*)ws;                    // 50000*64 half = 1,600,000 floats
    __half*       xwhB   = (__half*)(ws + 1600000);        // double buffer (fused layers)
    float*        agg3   = ws + 3200000;                   // 3,200,000 (fp32 layer-3 out)
    unsigned int* ell    = (unsigned int*)(ws + 6400000);  // 50000*48 u32 = 2,400,000 floats
    float*        dinv   = ws + 8800000;                   // 50,000
    int*          count  = (int*)(ws + 8850000);           // 50000*16 = 800,000 (line-padded)
    float*        pooled = ws + 9650000;                   // 8,192
    float*        cnt    = ws + 9658192;                   // 128
    // total ~9.66M * 4B = ~38.6 MB

    const int B = 256;

    (void)hipMemsetAsync(count, 0, N_NODES * CPAD * sizeof(int), stream);
    (void)hipMemsetAsync(pooled, 0, (N_GRAPHS * D + N_GRAPHS) * sizeof(float), stream);

    const int quadBlocks = 3125;  // 12500 waves = 12500 quads = 50000 rows exact

    // ELL build: 8 groups x 391 blocks; group = bid&7 owns one dst partition.
    ell_scatter<<<391 * NXCD, B, 0, stream>>>(src, dst, ew, count, ell);
    node_dinv<<<3125, B, 0, stream>>>(count, ell, dinv);

    // layer 1 gemm: xwhA = dinv .* (x @ W1)
    gemm_rows<<<quadBlocks, B, 0, stream>>>(x, W1, dinv, xwhA);
    // fused layer 1 agg + layer 2 gemm: xwhB = dinv .* (relu(A^(xwhA)+b1) @ W2)
    aggemm<<<quadBlocks, B, 0, stream>>>(count, ell, dinv, xwhA, b1, W2, xwhB);
    // fused layer 2 agg + layer 3 gemm: xwhA = dinv .* (relu(A^(xwhB)+b2) @ W3)
    aggemm<<<quadBlocks, B, 0, stream>>>(count, ell, dinv, xwhB, b2, W3, xwhA);
    // layer 3 aggregation (no relu): agg3 = A^(xwhA) + b3
    node_agg<<<quadBlocks, B, 0, stream>>>(count, ell, dinv, xwhA, b3, agg3);

    // global mean pool and classifier
    pool<<<196, B, 0, stream>>>(agg3, batch, pooled, cnt);
    final_lin<<<N_GRAPHS, 64, 0, stream>>>(pooled, cnt, Wlin, blin, out);
}

// Round 17
// 254.400 us; speedup vs baseline: 1.0630x; 1.0129x over previous
//
#include <hip/hip_runtime.h>
#include <hip/hip_fp16.h>

#define N_NODES   50000
#define N_EDGES   800000
#define D         64
#define N_CLASSES 10
#define N_GRAPHS  128
#define ELLW      48   // max in-degree bound: Poisson(16), P(any deg>=48) ~ 1e-6; input fixed
#define CPAD      16   // counters padded to one per 64B line (atomic line-serialization fix)
#define NXCD      8
#define DPART     (N_NODES / NXCD)   // 6250 dst nodes per XCD partition

// ELL entry is PACKED 4B: low16 = src node id (<50000<65536), high16 = ew as fp16.
// Activations are PRE-SCALED: xwh'[i] = dinv[i]*(h@W)[i] -> gather is dinv-free:
//   agg[i] = dv*( xwh'[i] + sum_j ew_j * xwh'[src_j] ) + b
// Gather is QUAD-ROW (round-15): SGPR meta, 32 row-gathers in flight, one quad
// per wave. Round-16: node_dinv folded into gemm_rows' prologue (its dispatch
// + 9.6MB ELL re-read deleted); layer-3 output agg3 stored fp16 (halves the
// pool round-trip). Dead ends (do not retry): scatter-fusion, pool-fusion,
// nt-loads, half2-lanes.

__device__ __forceinline__ float unpack_ew(int p) {
    return __half2float(__ushort_as_half((unsigned short)((unsigned)p >> 16)));
}

// ---------------- setup kernels ----------------

// XCD-partitioned scatter (round-2 proven form: ~47us, occ 62%). Round-4's
// nontemporal scan REGRESSED; ~31MB residual write traffic is structural
// (~1-2 entries per ELL line per fill window). Latency/atomic floor; leave it.
__global__ __launch_bounds__(256) void ell_scatter(const int* __restrict__ src,
                                                   const int* __restrict__ dst,
                                                   const float* __restrict__ ew,
                                                   int* __restrict__ count,
                                                   unsigned int* __restrict__ ell) {
    const int grp = blockIdx.x & (NXCD - 1);
    const int ord = blockIdx.x >> 3;          // 0..390
    const int lo  = grp * DPART;
#pragma unroll
    for (int i = 0; i < 8; ++i) {
        int e = ord * 2048 + i * 256 + threadIdx.x;
        if (e < N_EDGES) {
            int d = dst[e];
            if ((unsigned)(d - lo) < (unsigned)DPART) {
                int s = src[e];
                float w = ew[e];
                int c = atomicAdd(&count[d * CPAD], 1);
                if (c < ELLW) {
                    ell[d * ELLW + c] = (unsigned int)s |
                        ((unsigned int)__half_as_ushort(__float2half_rn(w)) << 16);
                }
            }
        }
    }
}

// ---------------- shared quad-row gather core (round-15 proven) ----------------

// PRECONDITION: r0 = 4*q with q a wave-uniform SGPR value. acc[r] =
// xwh'[r0+r] + sum_j ew_j * xwh'[src_j]. One batch loop to max of the 4
// counts. Meta via uniform s_load -> SGPR; clamps are s_cselect; p->0 slots:
// ew = 0.0, address hits hot row 0. 32 row-gathers in flight per batch.
__device__ __forceinline__ void gather_quad(const int* __restrict__ count,
                                            const unsigned int* __restrict__ ell,
                                            const __half* __restrict__ xwh,
                                            int r0, int lane, float acc[4]) {
    int cnt[4];
#pragma unroll
    for (int r = 0; r < 4; ++r) cnt[r] = min(count[(r0 + r) * CPAD], ELLW);
#pragma unroll
    for (int r = 0; r < 4; ++r)
        acc[r] = __half2float(xwh[(size_t)(r0 + r) * D + lane]);  // self (pre-scaled)
    int cm = max(max(cnt[0], cnt[1]), max(cnt[2], cnt[3]));
    for (int j = 0; j < cm; j += 8) {
        int p[4][8];
#pragma unroll
        for (int r = 0; r < 4; ++r) {
            const int4* m = (const int4*)(ell + (size_t)(r0 + r) * ELLW);
            int4 a0 = m[j / 4 + 0];   // uniform addr -> s_load_dwordx4
            int4 a1 = m[j / 4 + 1];
            p[r][0] = a0.x; p[r][1] = a0.y; p[r][2] = a0.z; p[r][3] = a0.w;
            p[r][4] = a1.x; p[r][5] = a1.y; p[r][6] = a1.z; p[r][7] = a1.w;
#pragma unroll
            for (int t = 0; t < 8; ++t)
                p[r][t] = (j + t < cnt[r]) ? p[r][t] : 0;  // s_cselect
        }
        float v[4][8];
#pragma unroll
        for (int r = 0; r < 4; ++r)
#pragma unroll
            for (int t = 0; t < 8; ++t)
                v[r][t] = __half2float(xwh[(size_t)(p[r][t] & 0xFFFF) * D + lane]);
#pragma unroll
        for (int r = 0; r < 4; ++r)
#pragma unroll
            for (int t = 0; t < 8; ++t)
                acc[r] = fmaf(v[r][t], unpack_ew(p[r][t]), acc[r]);
    }
}

// ---------------- per-layer kernels ----------------

// Layer-1 gemm + dinv build (round-16): xwh' = dinv[row]*(in @ W), and dinv
// itself is computed here (node_dinv's body x4: masked ELL slot read +
// shfl_xor reduce + rsqrt; ~60cyc/wave) and stored for the downstream
// kernels -- the separate node_dinv dispatch + its 9.6MB ELL re-read vanish.
// GEMM core is round-12's proven quad vector path.
__global__ __launch_bounds__(256) void gemm_rows(const float* __restrict__ in,
                                                 const float* __restrict__ W,
                                                 const int* __restrict__ count,
                                                 const unsigned int* __restrict__ ell,
                                                 float* __restrict__ dinv,
                                                 __half* __restrict__ xwh) {
    __shared__ float  Wl[D * D];      // 16KB
    __shared__ float4 xq[4][64];      // 4KB: per-wave quad stage
    for (int i = threadIdx.x; i < D * D; i += blockDim.x) Wl[i] = W[i];
    __syncthreads();

    const int lane = threadIdx.x & 63;
    const int wid  = threadIdx.x >> 6;
    float w[D];
#pragma unroll
    for (int k = 0; k < D; ++k) w[k] = Wl[k * D + lane];  // 2-way bank alias: free

    const int q = (blockIdx.x * blockDim.x + threadIdx.x) >> 6;  // quad id, exact
    const int r0 = q * 4;

    xq[wid][lane] = ((const float4*)(in + (size_t)r0 * D))[lane];  // 1KB coalesced

    // ---- dinv for the quad (deg = 1 + sum ew over slots) ----
    float dv0, dv1, dv2, dv3;
    {
        float s;
        int c0 = min(count[(r0 + 0) * CPAD], ELLW);
        s = (lane < c0) ? unpack_ew((int)ell[(size_t)(r0 + 0) * ELLW + lane]) : 0.0f;
#pragma unroll
        for (int off = 32; off >= 1; off >>= 1) s += __shfl_xor(s, off);
        dv0 = rsqrtf(1.0f + s);
        int c1 = min(count[(r0 + 1) * CPAD], ELLW);
        s = (lane < c1) ? unpack_ew((int)ell[(size_t)(r0 + 1) * ELLW + lane]) : 0.0f;
#pragma unroll
        for (int off = 32; off >= 1; off >>= 1) s += __shfl_xor(s, off);
        dv1 = rsqrtf(1.0f + s);
        int c2 = min(count[(r0 + 2) * CPAD], ELLW);
        s = (lane < c2) ? unpack_ew((int)ell[(size_t)(r0 + 2) * ELLW + lane]) : 0.0f;
#pragma unroll
        for (int off = 32; off >= 1; off >>= 1) s += __shfl_xor(s, off);
        dv2 = rsqrtf(1.0f + s);
        int c3 = min(count[(r0 + 3) * CPAD], ELLW);
        s = (lane < c3) ? unpack_ew((int)ell[(size_t)(r0 + 3) * ELLW + lane]) : 0.0f;
#pragma unroll
        for (int off = 32; off >= 1; off >>= 1) s += __shfl_xor(s, off);
        dv3 = rsqrtf(1.0f + s);
    }
    if (lane == 0)
        *(float4*)(dinv + r0) = make_float4(dv0, dv1, dv2, dv3);  // 16B aligned

    // ---- quad GEMM ----
    const float4* xr = (const float4*)xq[wid];
    float acc0 = 0.0f, acc1 = 0.0f, acc2 = 0.0f, acc3 = 0.0f;
#pragma unroll
    for (int k4 = 0; k4 < D / 4; ++k4) {
        float4 x0 = xr[0 * 16 + k4];  // uniform addr -> LDS broadcast
        float4 x1 = xr[1 * 16 + k4];
        float4 x2 = xr[2 * 16 + k4];
        float4 x3 = xr[3 * 16 + k4];
        float w0 = w[4 * k4 + 0], w1 = w[4 * k4 + 1];
        float w2 = w[4 * k4 + 2], w3 = w[4 * k4 + 3];
        acc0 = fmaf(x0.x, w0, acc0); acc0 = fmaf(x0.y, w1, acc0);
        acc0 = fmaf(x0.z, w2, acc0); acc0 = fmaf(x0.w, w3, acc0);
        acc1 = fmaf(x1.x, w0, acc1); acc1 = fmaf(x1.y, w1, acc1);
        acc1 = fmaf(x1.z, w2, acc1); acc1 = fmaf(x1.w, w3, acc1);
        acc2 = fmaf(x2.x, w0, acc2); acc2 = fmaf(x2.y, w1, acc2);
        acc2 = fmaf(x2.z, w2, acc2); acc2 = fmaf(x2.w, w3, acc2);
        acc3 = fmaf(x3.x, w0, acc3); acc3 = fmaf(x3.y, w1, acc3);
        acc3 = fmaf(x3.z, w2, acc3); acc3 = fmaf(x3.w, w3, acc3);
    }
    xwh[(size_t)(r0 + 0) * D + lane] = __float2half(acc0 * dv0);
    xwh[(size_t)(r0 + 1) * D + lane] = __float2half(acc1 * dv1);
    xwh[(size_t)(r0 + 2) * D + lane] = __float2half(acc2 * dv2);
    xwh[(size_t)(r0 + 3) * D + lane] = __float2half(acc3 * dv3);
}

// FUSED agg+gemm (layers 1->2 and 2->3), quad-row, one quad per wave
// (round-15 proven form).
__global__ __launch_bounds__(256) void aggemm(const int* __restrict__ count,
                                              const unsigned int* __restrict__ ell,
                                              const float* __restrict__ dinv,
                                              const __half* __restrict__ xin,
                                              const float* __restrict__ bias,
                                              const float* __restrict__ W,
                                              __half* __restrict__ xout) {
    __shared__ float Wl[D * D];        // 16KB
    __shared__ float rb[4][4][D];      // 4KB: per-wave, rows 0..3
    for (int i = threadIdx.x; i < D * D; i += blockDim.x) Wl[i] = W[i];
    __syncthreads();

    const int lane = threadIdx.x & 63;
    const int wid  = threadIdx.x >> 6;
    const int q = __builtin_amdgcn_readfirstlane(
        (blockIdx.x * blockDim.x + threadIdx.x) >> 6);   // quad id, SGPR
    const int r0 = q * 4;
    const float bv = bias[lane];

    float acc[4];
    gather_quad(count, ell, xin, r0, lane, acc);
    float dv[4];
#pragma unroll
    for (int r = 0; r < 4; ++r) dv[r] = dinv[r0 + r];
#pragma unroll
    for (int r = 0; r < 4; ++r)
        rb[wid][r][lane] = fmaxf(fmaf(acc[r], dv[r], bv), 0.0f);  // relu

    const float4* rq[4] = {(const float4*)rb[wid][0], (const float4*)rb[wid][1],
                           (const float4*)rb[wid][2], (const float4*)rb[wid][3]};
    float o0 = 0.0f, o1 = 0.0f, o2 = 0.0f, o3 = 0.0f;
#pragma unroll
    for (int k4 = 0; k4 < D / 4; ++k4) {
        float4 ra = rq[0][k4];  // uniform addr -> LDS broadcast
        float4 rbv = rq[1][k4];
        float4 rc = rq[2][k4];
        float4 rd = rq[3][k4];
        float w0 = Wl[(4 * k4 + 0) * D + lane];
        float w1 = Wl[(4 * k4 + 1) * D + lane];
        float w2 = Wl[(4 * k4 + 2) * D + lane];
        float w3 = Wl[(4 * k4 + 3) * D + lane];
        o0 = fmaf(ra.x, w0, o0);  o0 = fmaf(ra.y, w1, o0);
        o0 = fmaf(ra.z, w2, o0);  o0 = fmaf(ra.w, w3, o0);
        o1 = fmaf(rbv.x, w0, o1); o1 = fmaf(rbv.y, w1, o1);
        o1 = fmaf(rbv.z, w2, o1); o1 = fmaf(rbv.w, w3, o1);
        o2 = fmaf(rc.x, w0, o2);  o2 = fmaf(rc.y, w1, o2);
        o2 = fmaf(rc.z, w2, o2);  o2 = fmaf(rc.w, w3, o2);
        o3 = fmaf(rd.x, w0, o3);  o3 = fmaf(rd.y, w1, o3);
        o3 = fmaf(rd.z, w2, o3);  o3 = fmaf(rd.w, w3, o3);
    }
    xout[(size_t)(r0 + 0) * D + lane] = __float2half(o0 * dv[0]);
    xout[(size_t)(r0 + 1) * D + lane] = __float2half(o1 * dv[1]);
    xout[(size_t)(r0 + 2) * D + lane] = __float2half(o2 * dv[2]);
    xout[(size_t)(r0 + 3) * D + lane] = __float2half(o3 * dv[3]);
}

// Plain aggregation (layer-3 output), quad-row. Round-16: output fp16
// (feeds only mean-pool -> classifier; halves the pool round-trip traffic).
__global__ __launch_bounds__(256) void node_agg(const int* __restrict__ count,
                                                const unsigned int* __restrict__ ell,
                                                const float* __restrict__ dinv,
                                                const __half* __restrict__ xwh,
                                                const float* __restrict__ bias,
                                                __half* __restrict__ aggh) {
    const int lane = threadIdx.x & 63;
    const int q = __builtin_amdgcn_readfirstlane(
        (blockIdx.x * blockDim.x + threadIdx.x) >> 6);   // quad id, SGPR
    const int r0 = q * 4;
    const float bv = bias[lane];

    float acc[4];
    gather_quad(count, ell, xwh, r0, lane, acc);
#pragma unroll
    for (int r = 0; r < 4; ++r)
        aggh[(size_t)(r0 + r) * D + lane] =
            __float2half(fmaf(acc[r], dinv[r0 + r], bv));
}

// ---------------- pooling + classifier ----------------

// batch sorted: contiguous chunk per wave, register accumulate (fp32), flush
// per boundary. Input is fp16 (round-16).
__global__ __launch_bounds__(256) void pool(const __half* __restrict__ aggh,
                                            const int* __restrict__ batch,
                                            float* __restrict__ pooled,
                                            float* __restrict__ cnt) {
    const int lane = threadIdx.x & 63;
    const int gwave = (blockIdx.x * blockDim.x + threadIdx.x) >> 6;
    const int nw = (gridDim.x * blockDim.x) >> 6;
    const int chunk = (N_NODES + nw - 1) / nw;
    int r0 = gwave * chunk;
    int r1 = min(r0 + chunk, N_NODES);
    if (r0 >= r1) return;

    int g = batch[r0];
    float acc = 0.0f;
    int c = 0;
    for (int row = r0; row < r1; ++row) {
        int gg = batch[row];
        if (gg != g) {
            atomicAdd(&pooled[g * D + lane], acc);
            if (lane == 0) atomicAdd(&cnt[g], (float)c);
            g = gg; acc = 0.0f; c = 0;
        }
        acc += __half2float(aggh[(size_t)row * D + lane]);
        ++c;
    }
    atomicAdd(&pooled[g * D + lane], acc);
    if (lane == 0) atomicAdd(&cnt[g], (float)c);
}

__global__ __launch_bounds__(64) void final_lin(const float* __restrict__ pooled,
                                                const float* __restrict__ cnt,
                                                const float* __restrict__ Wlin,
                                                const float* __restrict__ blin,
                                                float* __restrict__ out) {
    __shared__ float row[D];
    int g = blockIdx.x;
    int t = threadIdx.x;
    float c = fmaxf(cnt[g], 1.0f);
    row[t] = pooled[g * D + t] / c;
    __syncthreads();
    if (t < N_CLASSES) {
        float acc = blin[t];
#pragma unroll
        for (int k = 0; k < D; ++k) acc = fmaf(row[k], Wlin[k * N_CLASSES + t], acc);
        out[g * N_CLASSES + t] = acc;
    }
}

// ---------------- launch ----------------

extern "C" void kernel_launch(void* const* d_in, const int* in_sizes, int n_in,
                              void* d_out, int out_size, void* d_ws, size_t ws_size,
                              hipStream_t stream) {
    const float* x     = (const float*)d_in[0];
    const int*   ei    = (const int*)d_in[1];
    const int*   src   = ei;
    const int*   dst   = ei + N_EDGES;
    const int*   batch = (const int*)d_in[2];
    const float* ew    = (const float*)d_in[3];
    const float* W1    = (const float*)d_in[4];
    const float* b1    = (const float*)d_in[5];
    const float* W2    = (const float*)d_in[6];
    const float* b2    = (const float*)d_in[7];
    const float* W3    = (const float*)d_in[8];
    const float* b3    = (const float*)d_in[9];
    const float* Wlin  = (const float*)d_in[10];
    const float* blin  = (const float*)d_in[11];
    float* out = (float*)d_out;

    // workspace layout (4B units)
    float*        ws     = (float*)d_ws;
    __half*       xwhA   = (__half*)ws;                    // 50000*64 half = 1,600,000 floats
    __half*       xwhB   = (__half*)(ws + 1600000);        // double buffer (fused layers)
    __half*       aggh   = (__half*)(ws + 3200000);        // layer-3 out, fp16 = 1,600,000 floats
    unsigned int* ell    = (unsigned int*)(ws + 4800000);  // 50000*48 u32 = 2,400,000 floats
    float*        dinv   = ws + 7200000;                   // 50,000
    int*          count  = (int*)(ws + 7250000);           // 50000*16 = 800,000 (line-padded)
    float*        pooled = ws + 8050000;                   // 8,192
    float*        cnt    = ws + 8058192;                   // 128
    // total ~8.06M * 4B = ~32.2 MB

    const int B = 256;

    (void)hipMemsetAsync(count, 0, N_NODES * CPAD * sizeof(int), stream);
    (void)hipMemsetAsync(pooled, 0, (N_GRAPHS * D + N_GRAPHS) * sizeof(float), stream);

    const int quadBlocks = 3125;  // 12500 waves = 12500 quads = 50000 rows exact

    // ELL build: 8 groups x 391 blocks; group = bid&7 owns one dst partition.
    ell_scatter<<<391 * NXCD, B, 0, stream>>>(src, dst, ew, count, ell);

    // layer 1 gemm + dinv build: xwhA = dinv .* (x @ W1), dinv written here
    gemm_rows<<<quadBlocks, B, 0, stream>>>(x, W1, count, ell, dinv, xwhA);
    // fused layer 1 agg + layer 2 gemm: xwhB = dinv .* (relu(A^(xwhA)+b1) @ W2)
    aggemm<<<quadBlocks, B, 0, stream>>>(count, ell, dinv, xwhA, b1, W2, xwhB);
    // fused layer 2 agg + layer 3 gemm: xwhA = dinv .* (relu(A^(xwhB)+b2) @ W3)
    aggemm<<<quadBlocks, B, 0, stream>>>(count, ell, dinv, xwhB, b2, W3, xwhA);
    // layer 3 aggregation (no relu), fp16 out: aggh = A^(xwhA) + b3
    node_agg<<<quadBlocks, B, 0, stream>>>(count, ell, dinv, xwhA, b3, aggh);

    // global mean pool and classifier
    pool<<<196, B, 0, stream>>>(aggh, batch, pooled, cnt);
    final_lin<<<N_GRAPHS, 64, 0, stream>>>(pooled, cnt, Wlin, blin, out);
}

// Round 18
// 242.850 us; speedup vs baseline: 1.1136x; 1.0476x over previous
//
#include <hip/hip_runtime.h>
#include <hip/hip_fp16.h>

#define N_NODES   50000
#define N_EDGES   800000
#define D         64
#define N_CLASSES 10
#define N_GRAPHS  128
#define ELLW      48   // max in-degree bound: Poisson(16), P(any deg>=48) ~ 1e-6; input fixed
#define CPAD      16   // counters padded to one per 64B line (atomic line-serialization fix)
#define NXCD      8
#define DPART     (N_NODES / NXCD)   // 6250 dst nodes per XCD partition

// ELL entry is PACKED 4B: low16 = src node id (<50000<65536), high16 = ew as fp16.
// Activations are PRE-SCALED: xwh'[i] = dinv[i]*(h@W)[i] -> gather is dinv-free:
//   agg[i] = dv*( xwh'[i] + sum_j ew_j * xwh'[src_j] ) + b
// Gather is QUAD-ROW (round-15): SGPR meta, 32 row-gathers in flight, one quad
// per wave. Round-16: dinv folded into gemm_rows; agg3 fp16. Round-18: pool +
// final_lin fused into one block-per-graph kernel (batch sorted -> binary
// search range; no atomics, no pooled/cnt arrays). Dead ends (do not retry):
// scatter-fusion, gather+pool-fusion, nt-loads, half2-lanes.

__device__ __forceinline__ float unpack_ew(int p) {
    return __half2float(__ushort_as_half((unsigned short)((unsigned)p >> 16)));
}

// ---------------- setup kernels ----------------

// XCD-partitioned scatter (round-2 proven form: ~46us, occ 62%). Round-4's
// nontemporal scan REGRESSED; ~31MB residual write traffic is structural
// (~1-2 entries per ELL line per fill window). Latency/atomic floor; leave it.
__global__ __launch_bounds__(256) void ell_scatter(const int* __restrict__ src,
                                                   const int* __restrict__ dst,
                                                   const float* __restrict__ ew,
                                                   int* __restrict__ count,
                                                   unsigned int* __restrict__ ell) {
    const int grp = blockIdx.x & (NXCD - 1);
    const int ord = blockIdx.x >> 3;          // 0..390
    const int lo  = grp * DPART;
#pragma unroll
    for (int i = 0; i < 8; ++i) {
        int e = ord * 2048 + i * 256 + threadIdx.x;
        if (e < N_EDGES) {
            int d = dst[e];
            if ((unsigned)(d - lo) < (unsigned)DPART) {
                int s = src[e];
                float w = ew[e];
                int c = atomicAdd(&count[d * CPAD], 1);
                if (c < ELLW) {
                    ell[d * ELLW + c] = (unsigned int)s |
                        ((unsigned int)__half_as_ushort(__float2half_rn(w)) << 16);
                }
            }
        }
    }
}

// ---------------- shared quad-row gather core (round-15 proven) ----------------

// PRECONDITION: r0 = 4*q with q a wave-uniform SGPR value. acc[r] =
// xwh'[r0+r] + sum_j ew_j * xwh'[src_j]. One batch loop to max of the 4
// counts. Meta via uniform s_load -> SGPR; clamps are s_cselect; p->0 slots:
// ew = 0.0, address hits hot row 0. 32 row-gathers in flight per batch.
__device__ __forceinline__ void gather_quad(const int* __restrict__ count,
                                            const unsigned int* __restrict__ ell,
                                            const __half* __restrict__ xwh,
                                            int r0, int lane, float acc[4]) {
    int cnt[4];
#pragma unroll
    for (int r = 0; r < 4; ++r) cnt[r] = min(count[(r0 + r) * CPAD], ELLW);
#pragma unroll
    for (int r = 0; r < 4; ++r)
        acc[r] = __half2float(xwh[(size_t)(r0 + r) * D + lane]);  // self (pre-scaled)
    int cm = max(max(cnt[0], cnt[1]), max(cnt[2], cnt[3]));
    for (int j = 0; j < cm; j += 8) {
        int p[4][8];
#pragma unroll
        for (int r = 0; r < 4; ++r) {
            const int4* m = (const int4*)(ell + (size_t)(r0 + r) * ELLW);
            int4 a0 = m[j / 4 + 0];   // uniform addr -> s_load_dwordx4
            int4 a1 = m[j / 4 + 1];
            p[r][0] = a0.x; p[r][1] = a0.y; p[r][2] = a0.z; p[r][3] = a0.w;
            p[r][4] = a1.x; p[r][5] = a1.y; p[r][6] = a1.z; p[r][7] = a1.w;
#pragma unroll
            for (int t = 0; t < 8; ++t)
                p[r][t] = (j + t < cnt[r]) ? p[r][t] : 0;  // s_cselect
        }
        float v[4][8];
#pragma unroll
        for (int r = 0; r < 4; ++r)
#pragma unroll
            for (int t = 0; t < 8; ++t)
                v[r][t] = __half2float(xwh[(size_t)(p[r][t] & 0xFFFF) * D + lane]);
#pragma unroll
        for (int r = 0; r < 4; ++r)
#pragma unroll
            for (int t = 0; t < 8; ++t)
                acc[r] = fmaf(v[r][t], unpack_ew(p[r][t]), acc[r]);
    }
}

// ---------------- per-layer kernels ----------------

// Layer-1 gemm + dinv build (round-16): xwh' = dinv[row]*(in @ W); dinv
// computed here (node_dinv's body x4) and stored for downstream kernels.
// GEMM core is round-12's proven quad vector path.
__global__ __launch_bounds__(256) void gemm_rows(const float* __restrict__ in,
                                                 const float* __restrict__ W,
                                                 const int* __restrict__ count,
                                                 const unsigned int* __restrict__ ell,
                                                 float* __restrict__ dinv,
                                                 __half* __restrict__ xwh) {
    __shared__ float  Wl[D * D];      // 16KB
    __shared__ float4 xq[4][64];      // 4KB: per-wave quad stage
    for (int i = threadIdx.x; i < D * D; i += blockDim.x) Wl[i] = W[i];
    __syncthreads();

    const int lane = threadIdx.x & 63;
    const int wid  = threadIdx.x >> 6;
    float w[D];
#pragma unroll
    for (int k = 0; k < D; ++k) w[k] = Wl[k * D + lane];  // 2-way bank alias: free

    const int q = (blockIdx.x * blockDim.x + threadIdx.x) >> 6;  // quad id, exact
    const int r0 = q * 4;

    xq[wid][lane] = ((const float4*)(in + (size_t)r0 * D))[lane];  // 1KB coalesced

    // ---- dinv for the quad (deg = 1 + sum ew over slots) ----
    float dv0, dv1, dv2, dv3;
    {
        float s;
        int c0 = min(count[(r0 + 0) * CPAD], ELLW);
        s = (lane < c0) ? unpack_ew((int)ell[(size_t)(r0 + 0) * ELLW + lane]) : 0.0f;
#pragma unroll
        for (int off = 32; off >= 1; off >>= 1) s += __shfl_xor(s, off);
        dv0 = rsqrtf(1.0f + s);
        int c1 = min(count[(r0 + 1) * CPAD], ELLW);
        s = (lane < c1) ? unpack_ew((int)ell[(size_t)(r0 + 1) * ELLW + lane]) : 0.0f;
#pragma unroll
        for (int off = 32; off >= 1; off >>= 1) s += __shfl_xor(s, off);
        dv1 = rsqrtf(1.0f + s);
        int c2 = min(count[(r0 + 2) * CPAD], ELLW);
        s = (lane < c2) ? unpack_ew((int)ell[(size_t)(r0 + 2) * ELLW + lane]) : 0.0f;
#pragma unroll
        for (int off = 32; off >= 1; off >>= 1) s += __shfl_xor(s, off);
        dv2 = rsqrtf(1.0f + s);
        int c3 = min(count[(r0 + 3) * CPAD], ELLW);
        s = (lane < c3) ? unpack_ew((int)ell[(size_t)(r0 + 3) * ELLW + lane]) : 0.0f;
#pragma unroll
        for (int off = 32; off >= 1; off >>= 1) s += __shfl_xor(s, off);
        dv3 = rsqrtf(1.0f + s);
    }
    if (lane == 0)
        *(float4*)(dinv + r0) = make_float4(dv0, dv1, dv2, dv3);  // 16B aligned

    // ---- quad GEMM ----
    const float4* xr = (const float4*)xq[wid];
    float acc0 = 0.0f, acc1 = 0.0f, acc2 = 0.0f, acc3 = 0.0f;
#pragma unroll
    for (int k4 = 0; k4 < D / 4; ++k4) {
        float4 x0 = xr[0 * 16 + k4];  // uniform addr -> LDS broadcast
        float4 x1 = xr[1 * 16 + k4];
        float4 x2 = xr[2 * 16 + k4];
        float4 x3 = xr[3 * 16 + k4];
        float w0 = w[4 * k4 + 0], w1 = w[4 * k4 + 1];
        float w2 = w[4 * k4 + 2], w3 = w[4 * k4 + 3];
        acc0 = fmaf(x0.x, w0, acc0); acc0 = fmaf(x0.y, w1, acc0);
        acc0 = fmaf(x0.z, w2, acc0); acc0 = fmaf(x0.w, w3, acc0);
        acc1 = fmaf(x1.x, w0, acc1); acc1 = fmaf(x1.y, w1, acc1);
        acc1 = fmaf(x1.z, w2, acc1); acc1 = fmaf(x1.w, w3, acc1);
        acc2 = fmaf(x2.x, w0, acc2); acc2 = fmaf(x2.y, w1, acc2);
        acc2 = fmaf(x2.z, w2, acc2); acc2 = fmaf(x2.w, w3, acc2);
        acc3 = fmaf(x3.x, w0, acc3); acc3 = fmaf(x3.y, w1, acc3);
        acc3 = fmaf(x3.z, w2, acc3); acc3 = fmaf(x3.w, w3, acc3);
    }
    xwh[(size_t)(r0 + 0) * D + lane] = __float2half(acc0 * dv0);
    xwh[(size_t)(r0 + 1) * D + lane] = __float2half(acc1 * dv1);
    xwh[(size_t)(r0 + 2) * D + lane] = __float2half(acc2 * dv2);
    xwh[(size_t)(r0 + 3) * D + lane] = __float2half(acc3 * dv3);
}

// FUSED agg+gemm (layers 1->2 and 2->3), quad-row, one quad per wave
// (round-15 proven form).
__global__ __launch_bounds__(256) void aggemm(const int* __restrict__ count,
                                              const unsigned int* __restrict__ ell,
                                              const float* __restrict__ dinv,
                                              const __half* __restrict__ xin,
                                              const float* __restrict__ bias,
                                              const float* __restrict__ W,
                                              __half* __restrict__ xout) {
    __shared__ float Wl[D * D];        // 16KB
    __shared__ float rb[4][4][D];      // 4KB: per-wave, rows 0..3
    for (int i = threadIdx.x; i < D * D; i += blockDim.x) Wl[i] = W[i];
    __syncthreads();

    const int lane = threadIdx.x & 63;
    const int wid  = threadIdx.x >> 6;
    const int q = __builtin_amdgcn_readfirstlane(
        (blockIdx.x * blockDim.x + threadIdx.x) >> 6);   // quad id, SGPR
    const int r0 = q * 4;
    const float bv = bias[lane];

    float acc[4];
    gather_quad(count, ell, xin, r0, lane, acc);
    float dv[4];
#pragma unroll
    for (int r = 0; r < 4; ++r) dv[r] = dinv[r0 + r];
#pragma unroll
    for (int r = 0; r < 4; ++r)
        rb[wid][r][lane] = fmaxf(fmaf(acc[r], dv[r], bv), 0.0f);  // relu

    const float4* rq[4] = {(const float4*)rb[wid][0], (const float4*)rb[wid][1],
                           (const float4*)rb[wid][2], (const float4*)rb[wid][3]};
    float o0 = 0.0f, o1 = 0.0f, o2 = 0.0f, o3 = 0.0f;
#pragma unroll
    for (int k4 = 0; k4 < D / 4; ++k4) {
        float4 ra = rq[0][k4];  // uniform addr -> LDS broadcast
        float4 rbv = rq[1][k4];
        float4 rc = rq[2][k4];
        float4 rd = rq[3][k4];
        float w0 = Wl[(4 * k4 + 0) * D + lane];
        float w1 = Wl[(4 * k4 + 1) * D + lane];
        float w2 = Wl[(4 * k4 + 2) * D + lane];
        float w3 = Wl[(4 * k4 + 3) * D + lane];
        o0 = fmaf(ra.x, w0, o0);  o0 = fmaf(ra.y, w1, o0);
        o0 = fmaf(ra.z, w2, o0);  o0 = fmaf(ra.w, w3, o0);
        o1 = fmaf(rbv.x, w0, o1); o1 = fmaf(rbv.y, w1, o1);
        o1 = fmaf(rbv.z, w2, o1); o1 = fmaf(rbv.w, w3, o1);
        o2 = fmaf(rc.x, w0, o2);  o2 = fmaf(rc.y, w1, o2);
        o2 = fmaf(rc.z, w2, o2);  o2 = fmaf(rc.w, w3, o2);
        o3 = fmaf(rd.x, w0, o3);  o3 = fmaf(rd.y, w1, o3);
        o3 = fmaf(rd.z, w2, o3);  o3 = fmaf(rd.w, w3, o3);
    }
    xout[(size_t)(r0 + 0) * D + lane] = __float2half(o0 * dv[0]);
    xout[(size_t)(r0 + 1) * D + lane] = __float2half(o1 * dv[1]);
    xout[(size_t)(r0 + 2) * D + lane] = __float2half(o2 * dv[2]);
    xout[(size_t)(r0 + 3) * D + lane] = __float2half(o3 * dv[3]);
}

// Plain aggregation (layer-3 output), quad-row, fp16 out (round-16).
__global__ __launch_bounds__(256) void node_agg(const int* __restrict__ count,
                                                const unsigned int* __restrict__ ell,
                                                const float* __restrict__ dinv,
                                                const __half* __restrict__ xwh,
                                                const float* __restrict__ bias,
                                                __half* __restrict__ aggh) {
    const int lane = threadIdx.x & 63;
    const int q = __builtin_amdgcn_readfirstlane(
        (blockIdx.x * blockDim.x + threadIdx.x) >> 6);   // quad id, SGPR
    const int r0 = q * 4;
    const float bv = bias[lane];

    float acc[4];
    gather_quad(count, ell, xwh, r0, lane, acc);
#pragma unroll
    for (int r = 0; r < 4; ++r)
        aggh[(size_t)(r0 + r) * D + lane] =
            __float2half(fmaf(acc[r], dinv[r0 + r], bv));
}

// ---------------- fused pool + classifier (round-18) ----------------

// One block per graph. batch is sorted -> binary-search [lo,hi); 4 waves sum
// rows per-lane (4-deep load pipeline, coalesced 128B/row); LDS-reduce; mean;
// in-block classifier. Deletes pool's atomics, pooled/cnt arrays + memset,
// and one dispatch. (NOT the cursed gather+pool fusion -- this fuses the two
// tiny epilogue kernels only.)
__global__ __launch_bounds__(256) void pool_lin(const __half* __restrict__ aggh,
                                                const int* __restrict__ batch,
                                                const float* __restrict__ Wlin,
                                                const float* __restrict__ blin,
                                                float* __restrict__ out) {
    __shared__ float red[4][D];
    __shared__ float row[D];
    const int g = blockIdx.x;
    const int lane = threadIdx.x & 63;
    const int wid  = threadIdx.x >> 6;

    // lower_bound(g), lower_bound(g+1) -- uniform, all threads redundantly
    int a = 0, b = N_NODES;
    while (a < b) { int m = (a + b) >> 1; if (batch[m] < g) a = m + 1; else b = m; }
    const int lo = a;
    b = N_NODES;
    while (a < b) { int m = (a + b) >> 1; if (batch[m] < g + 1) a = m + 1; else b = m; }
    const int hi = a;

    // wave wid sums rows lo+wid, lo+wid+4, ... ; 4 loads in flight
    float acc = 0.0f;
    int r = lo + wid;
    for (; r + 12 < hi; r += 16) {
        float v0 = __half2float(aggh[(size_t)(r + 0)  * D + lane]);
        float v1 = __half2float(aggh[(size_t)(r + 4)  * D + lane]);
        float v2 = __half2float(aggh[(size_t)(r + 8)  * D + lane]);
        float v3 = __half2float(aggh[(size_t)(r + 12) * D + lane]);
        acc += (v0 + v1) + (v2 + v3);
    }
    for (; r < hi; r += 4) acc += __half2float(aggh[(size_t)r * D + lane]);
    red[wid][lane] = acc;
    __syncthreads();

    if (wid == 0) {
        float s = (red[0][lane] + red[1][lane]) + (red[2][lane] + red[3][lane]);
        row[lane] = s / fmaxf((float)(hi - lo), 1.0f);
    }
    __syncthreads();

    if (threadIdx.x < N_CLASSES) {
        float o = blin[threadIdx.x];
#pragma unroll
        for (int k = 0; k < D; ++k)
            o = fmaf(row[k], Wlin[k * N_CLASSES + threadIdx.x], o);
        out[g * N_CLASSES + threadIdx.x] = o;
    }
}

// ---------------- launch ----------------

extern "C" void kernel_launch(void* const* d_in, const int* in_sizes, int n_in,
                              void* d_out, int out_size, void* d_ws, size_t ws_size,
                              hipStream_t stream) {
    const float* x     = (const float*)d_in[0];
    const int*   ei    = (const int*)d_in[1];
    const int*   src   = ei;
    const int*   dst   = ei + N_EDGES;
    const int*   batch = (const int*)d_in[2];
    const float* ew    = (const float*)d_in[3];
    const float* W1    = (const float*)d_in[4];
    const float* b1    = (const float*)d_in[5];
    const float* W2    = (const float*)d_in[6];
    const float* b2    = (const float*)d_in[7];
    const float* W3    = (const float*)d_in[8];
    const float* b3    = (const float*)d_in[9];
    const float* Wlin  = (const float*)d_in[10];
    const float* blin  = (const float*)d_in[11];
    float* out = (float*)d_out;

    // workspace layout (4B units)
    float*        ws     = (float*)d_ws;
    __half*       xwhA   = (__half*)ws;                    // 50000*64 half = 1,600,000 floats
    __half*       xwhB   = (__half*)(ws + 1600000);        // double buffer (fused layers)
    __half*       aggh   = (__half*)(ws + 3200000);        // layer-3 out, fp16 = 1,600,000 floats
    unsigned int* ell    = (unsigned int*)(ws + 4800000);  // 50000*48 u32 = 2,400,000 floats
    float*        dinv   = ws + 7200000;                   // 50,000
    int*          count  = (int*)(ws + 7250000);           // 50000*16 = 800,000 (line-padded)
    // total ~8.05M * 4B = ~32.2 MB

    const int B = 256;

    (void)hipMemsetAsync(count, 0, N_NODES * CPAD * sizeof(int), stream);

    const int quadBlocks = 3125;  // 12500 waves = 12500 quads = 50000 rows exact

    // ELL build: 8 groups x 391 blocks; group = bid&7 owns one dst partition.
    ell_scatter<<<391 * NXCD, B, 0, stream>>>(src, dst, ew, count, ell);

    // layer 1 gemm + dinv build: xwhA = dinv .* (x @ W1), dinv written here
    gemm_rows<<<quadBlocks, B, 0, stream>>>(x, W1, count, ell, dinv, xwhA);
    // fused layer 1 agg + layer 2 gemm: xwhB = dinv .* (relu(A^(xwhA)+b1) @ W2)
    aggemm<<<quadBlocks, B, 0, stream>>>(count, ell, dinv, xwhA, b1, W2, xwhB);
    // fused layer 2 agg + layer 3 gemm: xwhA = dinv .* (relu(A^(xwhB)+b2) @ W3)
    aggemm<<<quadBlocks, B, 0, stream>>>(count, ell, dinv, xwhB, b2, W3, xwhA);
    // layer 3 aggregation (no relu), fp16 out: aggh = A^(xwhA) + b3
    node_agg<<<quadBlocks, B, 0, stream>>>(count, ell, dinv, xwhA, b3, aggh);

    // fused graph-mean pool + classifier: one block per graph
    pool_lin<<<N_GRAPHS, B, 0, stream>>>(aggh, batch, Wlin, blin, out);
}

// Round 19
// 238.872 us; speedup vs baseline: 1.1321x; 1.0167x over previous
//
#include <hip/hip_runtime.h>
#include <hip/hip_fp16.h>

#define N_NODES   50000
#define N_EDGES   800000
#define D         64
#define N_CLASSES 10
#define N_GRAPHS  128
#define ELLW      48   // max in-degree bound: Poisson(16), P(any deg>=48) ~ 1e-6; input fixed
#define CPAD      16   // counters padded to one per 64B line (atomic line-serialization fix)
#define NXCD      8
#define DPART     (N_NODES / NXCD)   // 6250 dst nodes per XCD partition

// ELL entry is PACKED 4B: low16 = src node id (<50000<65536), high16 = ew as fp16.
// Activations are PRE-SCALED: xwh'[i] = dinv[i]*(h@W)[i] -> gather is dinv-free:
//   agg[i] = dv*( xwh'[i] + sum_j ew_j * xwh'[src_j] ) + b
// Gather is QUAD-ROW (round-15): SGPR meta, 32 row-gathers in flight. Round-19:
// gemm_rows (which already reads every padded counter for the dinv build)
// emits a DENSE clamped cntd[] -- the gathers were fetching 3.2MB of 64B-
// padded count lines each (16x amplification) and now read a quad's counts
// with one s_load_dwordx4. Dead ends (do not retry): scatter-fusion,
// gather+pool-fusion, nt-loads, half2-lanes.

__device__ __forceinline__ float unpack_ew(int p) {
    return __half2float(__ushort_as_half((unsigned short)((unsigned)p >> 16)));
}

// ---------------- setup kernels ----------------

// XCD-partitioned scatter (round-2 proven form: ~46us, occ 62%). Round-4's
// nontemporal scan REGRESSED; ~31MB residual write traffic is structural
// (~1-2 entries per ELL line per fill window). Latency/atomic floor; leave it.
__global__ __launch_bounds__(256) void ell_scatter(const int* __restrict__ src,
                                                   const int* __restrict__ dst,
                                                   const float* __restrict__ ew,
                                                   int* __restrict__ count,
                                                   unsigned int* __restrict__ ell) {
    const int grp = blockIdx.x & (NXCD - 1);
    const int ord = blockIdx.x >> 3;          // 0..390
    const int lo  = grp * DPART;
#pragma unroll
    for (int i = 0; i < 8; ++i) {
        int e = ord * 2048 + i * 256 + threadIdx.x;
        if (e < N_EDGES) {
            int d = dst[e];
            if ((unsigned)(d - lo) < (unsigned)DPART) {
                int s = src[e];
                float w = ew[e];
                int c = atomicAdd(&count[d * CPAD], 1);
                if (c < ELLW) {
                    ell[d * ELLW + c] = (unsigned int)s |
                        ((unsigned int)__half_as_ushort(__float2half_rn(w)) << 16);
                }
            }
        }
    }
}

// ---------------- shared quad-row gather core ----------------

// PRECONDITION: r0 = 4*q with q a wave-uniform SGPR value; cntd[] is DENSE and
// pre-clamped to ELLW (round-19: one s_load_dwordx4 per quad instead of 4
// padded-line reads). acc[r] = xwh'[r0+r] + sum_j ew_j * xwh'[src_j].
// Meta via uniform s_load -> SGPR; clamps are s_cselect; p->0 slots: ew = 0.0,
// address hits hot row 0. 32 row-gathers in flight per batch.
__device__ __forceinline__ void gather_quad(const int* __restrict__ cntd,
                                            const unsigned int* __restrict__ ell,
                                            const __half* __restrict__ xwh,
                                            int r0, int lane, float acc[4]) {
    int4 cq = *(const int4*)(cntd + r0);       // uniform 16B -> s_load_dwordx4
    int cnt[4] = {cq.x, cq.y, cq.z, cq.w};     // already ELLW-clamped
#pragma unroll
    for (int r = 0; r < 4; ++r)
        acc[r] = __half2float(xwh[(size_t)(r0 + r) * D + lane]);  // self (pre-scaled)
    int cm = max(max(cnt[0], cnt[1]), max(cnt[2], cnt[3]));
    for (int j = 0; j < cm; j += 8) {
        int p[4][8];
#pragma unroll
        for (int r = 0; r < 4; ++r) {
            const int4* m = (const int4*)(ell + (size_t)(r0 + r) * ELLW);
            int4 a0 = m[j / 4 + 0];   // uniform addr -> s_load_dwordx4
            int4 a1 = m[j / 4 + 1];
            p[r][0] = a0.x; p[r][1] = a0.y; p[r][2] = a0.z; p[r][3] = a0.w;
            p[r][4] = a1.x; p[r][5] = a1.y; p[r][6] = a1.z; p[r][7] = a1.w;
#pragma unroll
            for (int t = 0; t < 8; ++t)
                p[r][t] = (j + t < cnt[r]) ? p[r][t] : 0;  // s_cselect
        }
        float v[4][8];
#pragma unroll
        for (int r = 0; r < 4; ++r)
#pragma unroll
            for (int t = 0; t < 8; ++t)
                v[r][t] = __half2float(xwh[(size_t)(p[r][t] & 0xFFFF) * D + lane]);
#pragma unroll
        for (int r = 0; r < 4; ++r)
#pragma unroll
            for (int t = 0; t < 8; ++t)
                acc[r] = fmaf(v[r][t], unpack_ew(p[r][t]), acc[r]);
    }
}

// ---------------- per-layer kernels ----------------

// Layer-1 gemm + dinv + dense-count build (rounds 16/19): xwh' =
// dinv[row]*(in @ W); dinv and ELLW-clamped cntd computed here from the
// padded counters (read once instead of 3x by the gathers).
// GEMM core is round-12's proven quad vector path.
__global__ __launch_bounds__(256) void gemm_rows(const float* __restrict__ in,
                                                 const float* __restrict__ W,
                                                 const int* __restrict__ count,
                                                 const unsigned int* __restrict__ ell,
                                                 float* __restrict__ dinv,
                                                 int* __restrict__ cntd,
                                                 __half* __restrict__ xwh) {
    __shared__ float  Wl[D * D];      // 16KB
    __shared__ float4 xq[4][64];      // 4KB: per-wave quad stage
    for (int i = threadIdx.x; i < D * D; i += blockDim.x) Wl[i] = W[i];
    __syncthreads();

    const int lane = threadIdx.x & 63;
    const int wid  = threadIdx.x >> 6;
    float w[D];
#pragma unroll
    for (int k = 0; k < D; ++k) w[k] = Wl[k * D + lane];  // 2-way bank alias: free

    const int q = (blockIdx.x * blockDim.x + threadIdx.x) >> 6;  // quad id, exact
    const int r0 = q * 4;

    xq[wid][lane] = ((const float4*)(in + (size_t)r0 * D))[lane];  // 1KB coalesced

    // ---- dinv + dense count for the quad (deg = 1 + sum ew over slots) ----
    float dv0, dv1, dv2, dv3;
    int c0, c1, c2, c3;
    {
        float s;
        c0 = min(count[(r0 + 0) * CPAD], ELLW);
        s = (lane < c0) ? unpack_ew((int)ell[(size_t)(r0 + 0) * ELLW + lane]) : 0.0f;
#pragma unroll
        for (int off = 32; off >= 1; off >>= 1) s += __shfl_xor(s, off);
        dv0 = rsqrtf(1.0f + s);
        c1 = min(count[(r0 + 1) * CPAD], ELLW);
        s = (lane < c1) ? unpack_ew((int)ell[(size_t)(r0 + 1) * ELLW + lane]) : 0.0f;
#pragma unroll
        for (int off = 32; off >= 1; off >>= 1) s += __shfl_xor(s, off);
        dv1 = rsqrtf(1.0f + s);
        c2 = min(count[(r0 + 2) * CPAD], ELLW);
        s = (lane < c2) ? unpack_ew((int)ell[(size_t)(r0 + 2) * ELLW + lane]) : 0.0f;
#pragma unroll
        for (int off = 32; off >= 1; off >>= 1) s += __shfl_xor(s, off);
        dv2 = rsqrtf(1.0f + s);
        c3 = min(count[(r0 + 3) * CPAD], ELLW);
        s = (lane < c3) ? unpack_ew((int)ell[(size_t)(r0 + 3) * ELLW + lane]) : 0.0f;
#pragma unroll
        for (int off = 32; off >= 1; off >>= 1) s += __shfl_xor(s, off);
        dv3 = rsqrtf(1.0f + s);
    }
    if (lane == 0) {
        *(float4*)(dinv + r0) = make_float4(dv0, dv1, dv2, dv3);  // 16B aligned
        *(int4*)(cntd + r0)   = make_int4(c0, c1, c2, c3);        // dense, clamped
    }

    // ---- quad GEMM ----
    const float4* xr = (const float4*)xq[wid];
    float acc0 = 0.0f, acc1 = 0.0f, acc2 = 0.0f, acc3 = 0.0f;
#pragma unroll
    for (int k4 = 0; k4 < D / 4; ++k4) {
        float4 x0 = xr[0 * 16 + k4];  // uniform addr -> LDS broadcast
        float4 x1 = xr[1 * 16 + k4];
        float4 x2 = xr[2 * 16 + k4];
        float4 x3 = xr[3 * 16 + k4];
        float w0 = w[4 * k4 + 0], w1 = w[4 * k4 + 1];
        float w2 = w[4 * k4 + 2], w3 = w[4 * k4 + 3];
        acc0 = fmaf(x0.x, w0, acc0); acc0 = fmaf(x0.y, w1, acc0);
        acc0 = fmaf(x0.z, w2, acc0); acc0 = fmaf(x0.w, w3, acc0);
        acc1 = fmaf(x1.x, w0, acc1); acc1 = fmaf(x1.y, w1, acc1);
        acc1 = fmaf(x1.z, w2, acc1); acc1 = fmaf(x1.w, w3, acc1);
        acc2 = fmaf(x2.x, w0, acc2); acc2 = fmaf(x2.y, w1, acc2);
        acc2 = fmaf(x2.z, w2, acc2); acc2 = fmaf(x2.w, w3, acc2);
        acc3 = fmaf(x3.x, w0, acc3); acc3 = fmaf(x3.y, w1, acc3);
        acc3 = fmaf(x3.z, w2, acc3); acc3 = fmaf(x3.w, w3, acc3);
    }
    xwh[(size_t)(r0 + 0) * D + lane] = __float2half(acc0 * dv0);
    xwh[(size_t)(r0 + 1) * D + lane] = __float2half(acc1 * dv1);
    xwh[(size_t)(r0 + 2) * D + lane] = __float2half(acc2 * dv2);
    xwh[(size_t)(r0 + 3) * D + lane] = __float2half(acc3 * dv3);
}

// FUSED agg+gemm (layers 1->2 and 2->3), quad-row, one quad per wave
// (round-15 proven form; round-19 dense counts).
__global__ __launch_bounds__(256) void aggemm(const int* __restrict__ cntd,
                                              const unsigned int* __restrict__ ell,
                                              const float* __restrict__ dinv,
                                              const __half* __restrict__ xin,
                                              const float* __restrict__ bias,
                                              const float* __restrict__ W,
                                              __half* __restrict__ xout) {
    __shared__ float Wl[D * D];        // 16KB
    __shared__ float rb[4][4][D];      // 4KB: per-wave, rows 0..3
    for (int i = threadIdx.x; i < D * D; i += blockDim.x) Wl[i] = W[i];
    __syncthreads();

    const int lane = threadIdx.x & 63;
    const int wid  = threadIdx.x >> 6;
    const int q = __builtin_amdgcn_readfirstlane(
        (blockIdx.x * blockDim.x + threadIdx.x) >> 6);   // quad id, SGPR
    const int r0 = q * 4;
    const float bv = bias[lane];

    float acc[4];
    gather_quad(cntd, ell, xin, r0, lane, acc);
    float dv[4];
#pragma unroll
    for (int r = 0; r < 4; ++r) dv[r] = dinv[r0 + r];
#pragma unroll
    for (int r = 0; r < 4; ++r)
        rb[wid][r][lane] = fmaxf(fmaf(acc[r], dv[r], bv), 0.0f);  // relu

    const float4* rq[4] = {(const float4*)rb[wid][0], (const float4*)rb[wid][1],
                           (const float4*)rb[wid][2], (const float4*)rb[wid][3]};
    float o0 = 0.0f, o1 = 0.0f, o2 = 0.0f, o3 = 0.0f;
#pragma unroll
    for (int k4 = 0; k4 < D / 4; ++k4) {
        float4 ra = rq[0][k4];  // uniform addr -> LDS broadcast
        float4 rbv = rq[1][k4];
        float4 rc = rq[2][k4];
        float4 rd = rq[3][k4];
        float w0 = Wl[(4 * k4 + 0) * D + lane];
        float w1 = Wl[(4 * k4 + 1) * D + lane];
        float w2 = Wl[(4 * k4 + 2) * D + lane];
        float w3 = Wl[(4 * k4 + 3) * D + lane];
        o0 = fmaf(ra.x, w0, o0);  o0 = fmaf(ra.y, w1, o0);
        o0 = fmaf(ra.z, w2, o0);  o0 = fmaf(ra.w, w3, o0);
        o1 = fmaf(rbv.x, w0, o1); o1 = fmaf(rbv.y, w1, o1);
        o1 = fmaf(rbv.z, w2, o1); o1 = fmaf(rbv.w, w3, o1);
        o2 = fmaf(rc.x, w0, o2);  o2 = fmaf(rc.y, w1, o2);
        o2 = fmaf(rc.z, w2, o2);  o2 = fmaf(rc.w, w3, o2);
        o3 = fmaf(rd.x, w0, o3);  o3 = fmaf(rd.y, w1, o3);
        o3 = fmaf(rd.z, w2, o3);  o3 = fmaf(rd.w, w3, o3);
    }
    xout[(size_t)(r0 + 0) * D + lane] = __float2half(o0 * dv[0]);
    xout[(size_t)(r0 + 1) * D + lane] = __float2half(o1 * dv[1]);
    xout[(size_t)(r0 + 2) * D + lane] = __float2half(o2 * dv[2]);
    xout[(size_t)(r0 + 3) * D + lane] = __float2half(o3 * dv[3]);
}

// Plain aggregation (layer-3 output), quad-row, fp16 out (round-16).
__global__ __launch_bounds__(256) void node_agg(const int* __restrict__ cntd,
                                                const unsigned int* __restrict__ ell,
                                                const float* __restrict__ dinv,
                                                const __half* __restrict__ xwh,
                                                const float* __restrict__ bias,
                                                __half* __restrict__ aggh) {
    const int lane = threadIdx.x & 63;
    const int q = __builtin_amdgcn_readfirstlane(
        (blockIdx.x * blockDim.x + threadIdx.x) >> 6);   // quad id, SGPR
    const int r0 = q * 4;
    const float bv = bias[lane];

    float acc[4];
    gather_quad(cntd, ell, xwh, r0, lane, acc);
#pragma unroll
    for (int r = 0; r < 4; ++r)
        aggh[(size_t)(r0 + r) * D + lane] =
            __float2half(fmaf(acc[r], dinv[r0 + r], bv));
}

// ---------------- fused pool + classifier (round-18 proven) ----------------

// One block per graph. batch sorted -> binary-search [lo,hi); 4 waves sum rows
// per-lane (4-deep load pipeline); LDS-reduce; mean; in-block classifier.
__global__ __launch_bounds__(256) void pool_lin(const __half* __restrict__ aggh,
                                                const int* __restrict__ batch,
                                                const float* __restrict__ Wlin,
                                                const float* __restrict__ blin,
                                                float* __restrict__ out) {
    __shared__ float red[4][D];
    __shared__ float row[D];
    const int g = blockIdx.x;
    const int lane = threadIdx.x & 63;
    const int wid  = threadIdx.x >> 6;

    int a = 0, b = N_NODES;
    while (a < b) { int m = (a + b) >> 1; if (batch[m] < g) a = m + 1; else b = m; }
    const int lo = a;
    b = N_NODES;
    while (a < b) { int m = (a + b) >> 1; if (batch[m] < g + 1) a = m + 1; else b = m; }
    const int hi = a;

    float acc = 0.0f;
    int r = lo + wid;
    for (; r + 12 < hi; r += 16) {
        float v0 = __half2float(aggh[(size_t)(r + 0)  * D + lane]);
        float v1 = __half2float(aggh[(size_t)(r + 4)  * D + lane]);
        float v2 = __half2float(aggh[(size_t)(r + 8)  * D + lane]);
        float v3 = __half2float(aggh[(size_t)(r + 12) * D + lane]);
        acc += (v0 + v1) + (v2 + v3);
    }
    for (; r < hi; r += 4) acc += __half2float(aggh[(size_t)r * D + lane]);
    red[wid][lane] = acc;
    __syncthreads();

    if (wid == 0) {
        float s = (red[0][lane] + red[1][lane]) + (red[2][lane] + red[3][lane]);
        row[lane] = s / fmaxf((float)(hi - lo), 1.0f);
    }
    __syncthreads();

    if (threadIdx.x < N_CLASSES) {
        float o = blin[threadIdx.x];
#pragma unroll
        for (int k = 0; k < D; ++k)
            o = fmaf(row[k], Wlin[k * N_CLASSES + threadIdx.x], o);
        out[g * N_CLASSES + threadIdx.x] = o;
    }
}

// ---------------- launch ----------------

extern "C" void kernel_launch(void* const* d_in, const int* in_sizes, int n_in,
                              void* d_out, int out_size, void* d_ws, size_t ws_size,
                              hipStream_t stream) {
    const float* x     = (const float*)d_in[0];
    const int*   ei    = (const int*)d_in[1];
    const int*   src   = ei;
    const int*   dst   = ei + N_EDGES;
    const int*   batch = (const int*)d_in[2];
    const float* ew    = (const float*)d_in[3];
    const float* W1    = (const float*)d_in[4];
    const float* b1    = (const float*)d_in[5];
    const float* W2    = (const float*)d_in[6];
    const float* b2    = (const float*)d_in[7];
    const float* W3    = (const float*)d_in[8];
    const float* b3    = (const float*)d_in[9];
    const float* Wlin  = (const float*)d_in[10];
    const float* blin  = (const float*)d_in[11];
    float* out = (float*)d_out;

    // workspace layout (4B units)
    float*        ws     = (float*)d_ws;
    __half*       xwhA   = (__half*)ws;                    // 50000*64 half = 1,600,000 floats
    __half*       xwhB   = (__half*)(ws + 1600000);        // double buffer (fused layers)
    __half*       aggh   = (__half*)(ws + 3200000);        // layer-3 out, fp16 = 1,600,000 floats
    unsigned int* ell    = (unsigned int*)(ws + 4800000);  // 50000*48 u32 = 2,400,000 floats
    float*        dinv   = ws + 7200000;                   // 50,000
    int*          cntd   = (int*)(ws + 7250000);           // 50,000 dense clamped counts
    int*          count  = (int*)(ws + 7300000);           // 50000*16 = 800,000 (line-padded)
    // total ~8.1M * 4B = ~32.4 MB

    const int B = 256;

    (void)hipMemsetAsync(count, 0, N_NODES * CPAD * sizeof(int), stream);

    const int quadBlocks = 3125;  // 12500 waves = 12500 quads = 50000 rows exact

    // ELL build: 8 groups x 391 blocks; group = bid&7 owns one dst partition.
    ell_scatter<<<391 * NXCD, B, 0, stream>>>(src, dst, ew, count, ell);

    // layer 1 gemm + dinv + dense-count build
    gemm_rows<<<quadBlocks, B, 0, stream>>>(x, W1, count, ell, dinv, cntd, xwhA);
    // fused layer 1 agg + layer 2 gemm: xwhB = dinv .* (relu(A^(xwhA)+b1) @ W2)
    aggemm<<<quadBlocks, B, 0, stream>>>(cntd, ell, dinv, xwhA, b1, W2, xwhB);
    // fused layer 2 agg + layer 3 gemm: xwhA = dinv .* (relu(A^(xwhB)+b2) @ W3)
    aggemm<<<quadBlocks, B, 0, stream>>>(cntd, ell, dinv, xwhB, b2, W3, xwhA);
    // layer 3 aggregation (no relu), fp16 out: aggh = A^(xwhA) + b3
    node_agg<<<quadBlocks, B, 0, stream>>>(cntd, ell, dinv, xwhA, b3, aggh);

    // fused graph-mean pool + classifier: one block per graph
    pool_lin<<<N_GRAPHS, B, 0, stream>>>(aggh, batch, Wlin, blin, out);
}